// Round 5
// baseline (129.154 us; speedup 1.0000x reference)
//
#include <hip/hip_runtime.h>
#include <hip/hip_bf16.h>

#define HH 8
#define NN 2048
#define DD 64

typedef __attribute__((ext_vector_type(8))) short bf16x8;
typedef __attribute__((ext_vector_type(16))) float f32x16;
typedef __attribute__((ext_vector_type(8))) unsigned short u16x8;
typedef unsigned short ushort_t;

static __device__ __forceinline__ unsigned short f2bf(float x) {
    union { float f; unsigned u; } un; un.f = x;
    unsigned r = un.u + 0x7FFFu + ((un.u >> 16) & 1u);  // RNE
    return (unsigned short)(r >> 16);
}

// ---------------- ws layout (bytes) ----------------
#define OFF_Q  0u
#define OFF_K  2097152u
#define OFF_VT 4194304u
#define OFF_R  6291456u
#define OFF_P  6815744u          // partials: [1536 tasks][2 roles][32*65] f32
#define WS_NEED (OFF_P + 1536u*2u*2080u*4u)

// ---------------- pre-pass: f32->bf16 (q,k,rpe) + V transpose ----------------
#define NQ4 262144   // 8*2048*64/4
#define NR4 65520    // 4095*64/4
#define CVT_BLOCKS 2305
__global__ void pre_kernel(const float* __restrict__ q, const float* __restrict__ k,
                           const float* __restrict__ r, const float* __restrict__ v,
                           ushort_t* __restrict__ ws) {
    __shared__ __align__(16) ushort_t T[64][72];
    if (blockIdx.x < CVT_BLOCKS) {
        int idx = blockIdx.x * 256 + threadIdx.x;
        const float* src; ushort_t* dst; int off;
        if (idx < NQ4) { src = q; dst = (ushort_t*)((char*)ws + OFF_Q); off = idx; }
        else if (idx < 2 * NQ4) { src = k; dst = (ushort_t*)((char*)ws + OFF_K); off = idx - NQ4; }
        else if (idx < 2 * NQ4 + NR4) { src = r; dst = (ushort_t*)((char*)ws + OFF_R); off = idx - 2 * NQ4; }
        else return;
        float4 f = *(const float4*)&src[4 * (size_t)off];
        ushort4 u; u.x = f2bf(f.x); u.y = f2bf(f.y); u.z = f2bf(f.z); u.w = f2bf(f.w);
        *(ushort4*)&dst[4 * (size_t)off] = u;
    } else {
        ushort_t* vt = (ushort_t*)((char*)ws + OFF_VT);
        const int bb = blockIdx.x - CVT_BLOCKS;          // 0..255
        const int h = bb >> 5;
        const int n0 = (bb & 31) * 64;
        const int tid = threadIdx.x;
        const float* vh = v + (size_t)h * NN * DD;
        #pragma unroll
        for (int p = 0; p < 4; ++p) {
            int c = tid + 256 * p; int rr = c >> 4, dc = (c & 15) << 2;
            float4 f = *(const float4*)&vh[(size_t)(n0 + rr) * DD + dc];
            T[dc + 0][rr] = f2bf(f.x); T[dc + 1][rr] = f2bf(f.y);
            T[dc + 2][rr] = f2bf(f.z); T[dc + 3][rr] = f2bf(f.w);
        }
        __syncthreads();
        #pragma unroll
        for (int p = 0; p < 2; ++p) {
            int c = tid + 256 * p; int d = c >> 3, nn = (c & 7) << 3;
            *(u16x8*)&vt[((size_t)h * 64 + d) * NN + n0 + nn] = *(const u16x8*)&T[d][nn];
        }
    }
}

// ---------------- main kernel: barrier-free, wave-autonomous, 32x32x16 MFMA ----------------
// 768 blocks x 128 threads (2 waves). Wave-task = (stream s, chunk c):
//   s: head = s&7, p = s>>3; stream = tile p (njtB units) then tile 63-p; 33 units total.
//   chunk c in [0,6): units [u0,u1) = [(33c+5)/6, (33c+38)/6)  -> sizes 6/5/6/5/6/5.
// A wave computes full 32-row x 64-col j-units: S=QK^T (2 tiles), T=Q*band^T (3 tiles),
// Toeplitz shear via wave-private LDS, W -> LDS transpose -> PV A-frags, PV + denom MFMA.
// All B/A fragments load straight from global (bf16, pre-converted). No __syncthreads.
__global__ __launch_bounds__(128, 2)
void fastmax_main(const ushort_t* __restrict__ wsb, float* __restrict__ wsPart)
{
    __shared__ __align__(16) float    Ts[2][96 * 34];   // wave-private, col-major [bw][r], stride 34
    __shared__ __align__(16) ushort_t Ws[2][32 * 96];   // wave-private, row-major [m][k], stride 96

    const ushort_t* qb  = (const ushort_t*)((const char*)wsb + OFF_Q);
    const ushort_t* kb  = (const ushort_t*)((const char*)wsb + OFF_K);
    const ushort_t* vtb = (const ushort_t*)((const char*)wsb + OFF_VT);
    const ushort_t* rb  = (const ushort_t*)((const char*)wsb + OFF_R);

    const int tid = threadIdx.x;
    const int wv  = tid >> 6;            // wave in block
    const int l   = tid & 63;
    const int ln  = l & 31;              // lane-in-half: MFMA m/n index
    const int h2  = l >> 5;              // half-wave: k-group / row offset
    float*    tsW = &Ts[wv][0];
    ushort_t* wsW = &Ws[wv][0];

    const int wtask = blockIdx.x * 2 + wv;        // 0..1535
    const int s     = wtask / 6;
    const int c     = wtask - 6 * s;
    const int head  = s & 7;
    const int p     = s >> 3;                     // 0..31
    const int u0    = (33 * c + 5) / 6;
    const int u1    = (33 * c + 38) / 6;
    const int njtB  = (p >> 1) + 1;

    const ushort_t* qh  = qb  + (size_t)head * NN * DD;
    const ushort_t* kh  = kb  + (size_t)head * NN * DD;
    const ushort_t* vth = vtb + (size_t)head * DD * NN;

    // denom constant B-frag: B[k][0]=1 else 0  -> lane n==0 holds ones
    const short one = (ln == 0) ? (short)0x3F80 : (short)0;
    const bf16x8 dfrag = {one, one, one, one, one, one, one, one};

    #pragma unroll 1
    for (int role = 0; role < 2; ++role) {
        const int tile = role ? (63 - p) : p;
        int jlo = role ? ((u0 > njtB ? u0 : njtB) - njtB) : u0;
        int jhi = role ? (u1 - njtB) : (u1 < njtB ? u1 : njtB);
        if (jlo >= jhi) continue;
        const int i0 = tile * 32;

        // Q A-frags (const over j): A[m=ln][k=16f+8h2+j]
        bf16x8 qf0 = *(const bf16x8*)&qh[(i0 + ln) * DD +  0 + 8 * h2];
        bf16x8 qf1 = *(const bf16x8*)&qh[(i0 + ln) * DD + 16 + 8 * h2];
        bf16x8 qf2 = *(const bf16x8*)&qh[(i0 + ln) * DD + 32 + 8 * h2];
        bf16x8 qf3 = *(const bf16x8*)&qh[(i0 + ln) * DD + 48 + 8 * h2];

        f32x16 acc0 = {0,0,0,0,0,0,0,0,0,0,0,0,0,0,0,0};
        f32x16 acc1 = {0,0,0,0,0,0,0,0,0,0,0,0,0,0,0,0};
        f32x16 accD = {0,0,0,0,0,0,0,0,0,0,0,0,0,0,0,0};

        for (int jt = jlo; jt < jhi; ++jt) {
            const int j0 = jt * 64;
            const int relbase = i0 - j0 + 1984;       // >= 1984

            // ---- S = Q K^T : 2 n-tiles, 4 k-steps; B[k][n]=K[n][k] straight from global
            f32x16 s0 = {0,0,0,0,0,0,0,0,0,0,0,0,0,0,0,0};
            f32x16 s1 = {0,0,0,0,0,0,0,0,0,0,0,0,0,0,0,0};
            {
                const ushort_t* k0p = &kh[(j0 + ln) * DD + 8 * h2];
                const ushort_t* k1p = &kh[(j0 + 32 + ln) * DD + 8 * h2];
                bf16x8 b;
                b = *(const bf16x8*)(k0p +  0); s0 = __builtin_amdgcn_mfma_f32_32x32x16_bf16(qf0, b, s0, 0, 0, 0);
                b = *(const bf16x8*)(k0p + 16); s0 = __builtin_amdgcn_mfma_f32_32x32x16_bf16(qf1, b, s0, 0, 0, 0);
                b = *(const bf16x8*)(k0p + 32); s0 = __builtin_amdgcn_mfma_f32_32x32x16_bf16(qf2, b, s0, 0, 0, 0);
                b = *(const bf16x8*)(k0p + 48); s0 = __builtin_amdgcn_mfma_f32_32x32x16_bf16(qf3, b, s0, 0, 0, 0);
                b = *(const bf16x8*)(k1p +  0); s1 = __builtin_amdgcn_mfma_f32_32x32x16_bf16(qf0, b, s1, 0, 0, 0);
                b = *(const bf16x8*)(k1p + 16); s1 = __builtin_amdgcn_mfma_f32_32x32x16_bf16(qf1, b, s1, 0, 0, 0);
                b = *(const bf16x8*)(k1p + 32); s1 = __builtin_amdgcn_mfma_f32_32x32x16_bf16(qf2, b, s1, 0, 0, 0);
                b = *(const bf16x8*)(k1p + 48); s1 = __builtin_amdgcn_mfma_f32_32x32x16_bf16(qf3, b, s1, 0, 0, 0);
            }

            // ---- T = Q band^T : 3 bw-tiles; band rows from global (clamped pad row)
            #pragma unroll
            for (int bt = 0; bt < 3; ++bt) {
                int row = relbase + 32 * bt + ln;
                if (row > 4094) row = 4094;           // read-only pad, bw=95 never gathered
                const ushort_t* bp = &rb[row * DD + 8 * h2];
                f32x16 t = {0,0,0,0,0,0,0,0,0,0,0,0,0,0,0,0};
                bf16x8 b;
                b = *(const bf16x8*)(bp +  0); t = __builtin_amdgcn_mfma_f32_32x32x16_bf16(qf0, b, t, 0, 0, 0);
                b = *(const bf16x8*)(bp + 16); t = __builtin_amdgcn_mfma_f32_32x32x16_bf16(qf1, b, t, 0, 0, 0);
                b = *(const bf16x8*)(bp + 32); t = __builtin_amdgcn_mfma_f32_32x32x16_bf16(qf2, b, t, 0, 0, 0);
                b = *(const bf16x8*)(bp + 48); t = __builtin_amdgcn_mfma_f32_32x32x16_bf16(qf3, b, t, 0, 0, 0);
                // col-major store: Ts[bw][r], b64 pairs (rows r, r+1)
                float* base = tsW + (32 * bt + ln) * 34 + 4 * h2;
                #pragma unroll
                for (int p2 = 0; p2 < 8; ++p2) {
                    int reg = 2 * p2;
                    int r = (reg & 3) + 8 * (reg >> 2);
                    *(float2*)(base + r) = make_float2(t[reg], t[reg + 1]);
                }
            }

            // ---- Toeplitz gather + Taylor weight + causal mask -> Ws (bf16, A-layout rows)
            #pragma unroll
            for (int nt = 0; nt < 2; ++nt) {
                const f32x16 sv = nt ? s1 : s0;
                const int cloc = 32 * nt + ln;
                const int gbase = 2142 - 34 * cloc;   // 34*(63-cloc)
                #pragma unroll
                for (int reg = 0; reg < 16; ++reg) {
                    int rp = (reg & 3) + 8 * (reg >> 2) + 4 * h2;
                    float tv = tsW[gbase + 35 * rp];  // Ts[rp-cloc+63][rp]
                    float sx = sv[reg] + tv;
                    float wx = 1.0f + sx + 0.5f * sx * sx;
                    if (j0 + cloc > i0 + rp) wx = 0.0f;
                    wsW[rp * 96 + cloc] = f2bf(wx);
                }
            }

            // ---- PV += W * [V^T ; ones-col] : A-frags from Ws, B-frags from global vtb
            {
                bf16x8 wf0 = *(const bf16x8*)&wsW[ln * 96 +  0 + 8 * h2];
                bf16x8 wf1 = *(const bf16x8*)&wsW[ln * 96 + 16 + 8 * h2];
                bf16x8 wf2 = *(const bf16x8*)&wsW[ln * 96 + 32 + 8 * h2];
                bf16x8 wf3 = *(const bf16x8*)&wsW[ln * 96 + 48 + 8 * h2];
                const ushort_t* v0p = &vth[(size_t)ln * NN + j0 + 8 * h2];
                const ushort_t* v1p = &vth[(size_t)(ln + 32) * NN + j0 + 8 * h2];
                bf16x8 b;
                b = *(const bf16x8*)(v0p +  0); acc0 = __builtin_amdgcn_mfma_f32_32x32x16_bf16(wf0, b, acc0, 0, 0, 0);
                b = *(const bf16x8*)(v0p + 16); acc0 = __builtin_amdgcn_mfma_f32_32x32x16_bf16(wf1, b, acc0, 0, 0, 0);
                b = *(const bf16x8*)(v0p + 32); acc0 = __builtin_amdgcn_mfma_f32_32x32x16_bf16(wf2, b, acc0, 0, 0, 0);
                b = *(const bf16x8*)(v0p + 48); acc0 = __builtin_amdgcn_mfma_f32_32x32x16_bf16(wf3, b, acc0, 0, 0, 0);
                b = *(const bf16x8*)(v1p +  0); acc1 = __builtin_amdgcn_mfma_f32_32x32x16_bf16(wf0, b, acc1, 0, 0, 0);
                b = *(const bf16x8*)(v1p + 16); acc1 = __builtin_amdgcn_mfma_f32_32x32x16_bf16(wf1, b, acc1, 0, 0, 0);
                b = *(const bf16x8*)(v1p + 32); acc1 = __builtin_amdgcn_mfma_f32_32x32x16_bf16(wf2, b, acc1, 0, 0, 0);
                b = *(const bf16x8*)(v1p + 48); acc1 = __builtin_amdgcn_mfma_f32_32x32x16_bf16(wf3, b, acc1, 0, 0, 0);
                accD = __builtin_amdgcn_mfma_f32_32x32x16_bf16(wf0, dfrag, accD, 0, 0, 0);
                accD = __builtin_amdgcn_mfma_f32_32x32x16_bf16(wf1, dfrag, accD, 0, 0, 0);
                accD = __builtin_amdgcn_mfma_f32_32x32x16_bf16(wf2, dfrag, accD, 0, 0, 0);
                accD = __builtin_amdgcn_mfma_f32_32x32x16_bf16(wf3, dfrag, accD, 0, 0, 0);
            }
        }

        // ---- flush partial [32 rows][65] (64 numerator cols + denom)
        {
            float* dst = wsPart + ((size_t)wtask * 2 + role) * 2080;
            #pragma unroll
            for (int reg = 0; reg < 16; ++reg) {
                int rr = (reg & 3) + 8 * (reg >> 2) + 4 * h2;
                dst[rr * 65 + ln]      = acc0[reg];
                dst[rr * 65 + 32 + ln] = acc1[reg];
                if (ln == 0) dst[rr * 65 + 64] = accD[reg];
            }
        }
    }
}

// ---------------- combine: per (head,tile) sum <=6 partials, divide, write ----------------
__global__ void combine_kernel(const float* __restrict__ wsPart, float* __restrict__ outg) {
    const int blk  = blockIdx.x;             // 0..511
    const int head = blk >> 6;
    const int t    = blk & 63;
    const int p    = (t < 63 - t) ? t : 63 - t;
    const int role = (t == p) ? 0 : 1;
    const int s    = p * 8 + head;
    const int njtB = (p >> 1) + 1;
    const float* P[6]; int nP = 0;
    #pragma unroll
    for (int c = 0; c < 6; ++c) {
        int u0 = (33 * c + 5) / 6, u1 = (33 * c + 38) / 6;
        bool valid = role ? (u1 > njtB) : (u0 < njtB);
        if (valid) P[nP++] = wsPart + ((size_t)(s * 6 + c) * 2 + role) * 2080;
    }
    float* oh = outg + (size_t)head * NN * DD;
    #pragma unroll
    for (int e2 = 0; e2 < 8; ++e2) {
        int idx = threadIdx.x + 256 * e2;    // 0..2047
        int r = idx >> 6, d = idx & 63;
        float num = 0.f, den = 0.f;
        for (int q2 = 0; q2 < nP; ++q2) {
            num += P[q2][r * 65 + d];
            den += P[q2][r * 65 + 64];
        }
        oh[(size_t)(t * 32 + r) * DD + d] = num / den;
    }
}

// ---------------- fallback (round-2 proven kernel, no ws) ----------------
typedef __attribute__((ext_vector_type(4))) float f32x4;
__global__ __launch_bounds__(256, 2)
void fastmax_fallback(const float* __restrict__ qg0, const float* __restrict__ kg0,
                      const float* __restrict__ vg0, const float* __restrict__ rg,
                      float* __restrict__ outg)
{
    __shared__ __align__(16) ushort_t Qs[32][72];
    __shared__ __align__(16) ushort_t Ks[64][72];
    __shared__ __align__(16) ushort_t Bs[96][72];
    __shared__ __align__(16) ushort_t Vts[96][72];
    __shared__ __align__(16) float    Tsf[32][97];
    __shared__ __align__(16) ushort_t Wsf[32][72];
    __shared__ float denomLds[32];

    const int tid = threadIdx.x;
    const int w = tid >> 6, l = tid & 63, lq = l >> 4, ln = l & 15;
    const int head = blockIdx.x & 7, ib = blockIdx.x >> 3;
    const int it = 63 - ib, i0 = it * 32, njt = (it >> 1) + 1;
    const float* qg = qg0 + (size_t)head * NN * DD;
    const float* kg = kg0 + (size_t)head * NN * DD;
    const float* vg = vg0 + (size_t)head * NN * DD;
    float* og = outg + (size_t)head * NN * DD;
    {
        #pragma unroll
        for (int p = 0; p < 2; ++p) {
            int c = tid + 256 * p; int r = c >> 4, dc = (c & 15) << 2;
            float4 f = *(const float4*)&qg[(size_t)(i0 + r) * DD + dc];
            ushort4 u; u.x = f2bf(f.x); u.y = f2bf(f.y); u.z = f2bf(f.z); u.w = f2bf(f.w);
            *(ushort4*)&Qs[r][dc] = u;
        }
        for (int idx = tid; idx < 32 * 72; idx += 256) {
            int rr = idx / 72, cc = idx - rr * 72;
            Vts[64 + rr][cc] = (rr == 0) ? (ushort_t)0x3F80 : (ushort_t)0;
        }
    }
    f32x4 a0 = {0,0,0,0}, a1 = {0,0,0,0}, a2 = {0,0,0,0};
    const int pr = w & 1, rt = w & 1, cp = w >> 1;
    for (int jt = 0; jt < njt; ++jt) {
        const int j0 = jt * 64;
        __syncthreads();
        #pragma unroll
        for (int p = 0; p < 4; ++p) {
            int c = tid + 256 * p; int r = c >> 4, dc = (c & 15) << 2;
            float4 f = *(const float4*)&kg[(size_t)(j0 + r) * DD + dc];
            ushort4 u; u.x = f2bf(f.x); u.y = f2bf(f.y); u.z = f2bf(f.z); u.w = f2bf(f.w);
            *(ushort4*)&Ks[r][dc] = u;
        }
        const int relbase = i0 - j0 + 1984;
        #pragma unroll
        for (int p = 0; p < 6; ++p) {
            int c = tid + 256 * p; int r = c >> 4, dc = (c & 15) << 2;
            int row = relbase + r; if (row > 4094) row = 4094;
            float4 f = *(const float4*)&rg[(size_t)row * DD + dc];
            ushort4 u; u.x = f2bf(f.x); u.y = f2bf(f.y); u.z = f2bf(f.z); u.w = f2bf(f.w);
            *(ushort4*)&Bs[r][dc] = u;
        }
        #pragma unroll
        for (int p = 0; p < 4; ++p) {
            int c = tid + 256 * p; int r = c >> 4, dc = (c & 15) << 2;
            float4 f = *(const float4*)&vg[(size_t)(j0 + r) * DD + dc];
            Vts[dc + 0][r] = f2bf(f.x); Vts[dc + 1][r] = f2bf(f.y);
            Vts[dc + 2][r] = f2bf(f.z); Vts[dc + 3][r] = f2bf(f.w);
        }
        __syncthreads();
        f32x4 s0 = {0,0,0,0}, s1 = {0,0,0,0};
        #pragma unroll
        for (int ks = 0; ks < 2; ++ks) {
            bf16x8 a = *(const bf16x8*)&Qs[16 * rt + ln][32 * ks + 8 * lq];
            bf16x8 b0 = *(const bf16x8*)&Ks[32 * cp + ln][32 * ks + 8 * lq];
            bf16x8 b1 = *(const bf16x8*)&Ks[32 * cp + 16 + ln][32 * ks + 8 * lq];
            s0 = __builtin_amdgcn_mfma_f32_16x16x32_bf16(a, b0, s0, 0, 0, 0);
            s1 = __builtin_amdgcn_mfma_f32_16x16x32_bf16(a, b1, s1, 0, 0, 0);
        }
        #pragma unroll
        for (int kk = 0; kk < 3; ++kk) {
            int bt = (w >> 1) + 2 * kk;
            f32x4 t = {0,0,0,0};
            #pragma unroll
            for (int ks = 0; ks < 2; ++ks) {
                bf16x8 a = *(const bf16x8*)&Qs[16 * rt + ln][32 * ks + 8 * lq];
                bf16x8 b = *(const bf16x8*)&Bs[16 * bt + ln][32 * ks + 8 * lq];
                t = __builtin_amdgcn_mfma_f32_16x16x32_bf16(a, b, t, 0, 0, 0);
            }
            #pragma unroll
            for (int e = 0; e < 4; ++e) Tsf[16 * rt + 4 * lq + e][16 * bt + ln] = t[e];
        }
        __syncthreads();
        #pragma unroll
        for (int ct2 = 0; ct2 < 2; ++ct2) {
            f32x4 sv = ct2 ? s1 : s0;
            int c_loc = 32 * cp + 16 * ct2 + ln, j = j0 + c_loc;
            #pragma unroll
            for (int e = 0; e < 4; ++e) {
                int r_loc = 16 * rt + 4 * lq + e, i = i0 + r_loc;
                float s = sv[e] + Tsf[r_loc][r_loc - c_loc + 63];
                float wv = 1.0f + s + 0.5f * s * s;
                if (j > i) wv = 0.0f;
                Wsf[r_loc][c_loc] = f2bf(wv);
            }
        }
        __syncthreads();
        {
            bf16x8 af0 = *(const bf16x8*)&Wsf[16 * pr + ln][ 0 + 8 * lq];
            bf16x8 af1 = *(const bf16x8*)&Wsf[16 * pr + ln][32 + 8 * lq];
            int pn0 = w >> 1; bf16x8 b;
            b = *(const bf16x8*)&Vts[16 * (pn0 + 0) + ln][ 0 + 8 * lq];
            a0 = __builtin_amdgcn_mfma_f32_16x16x32_bf16(af0, b, a0, 0, 0, 0);
            b = *(const bf16x8*)&Vts[16 * (pn0 + 0) + ln][32 + 8 * lq];
            a0 = __builtin_amdgcn_mfma_f32_16x16x32_bf16(af1, b, a0, 0, 0, 0);
            b = *(const bf16x8*)&Vts[16 * (pn0 + 2) + ln][ 0 + 8 * lq];
            a1 = __builtin_amdgcn_mfma_f32_16x16x32_bf16(af0, b, a1, 0, 0, 0);
            b = *(const bf16x8*)&Vts[16 * (pn0 + 2) + ln][32 + 8 * lq];
            a1 = __builtin_amdgcn_mfma_f32_16x16x32_bf16(af1, b, a1, 0, 0, 0);
            b = *(const bf16x8*)&Vts[16 * (pn0 + 4) + ln][ 0 + 8 * lq];
            a2 = __builtin_amdgcn_mfma_f32_16x16x32_bf16(af0, b, a2, 0, 0, 0);
            b = *(const bf16x8*)&Vts[16 * (pn0 + 4) + ln][32 + 8 * lq];
            a2 = __builtin_amdgcn_mfma_f32_16x16x32_bf16(af1, b, a2, 0, 0, 0);
        }
    }
    if (w < 2 && ln == 0) {
        #pragma unroll
        for (int e = 0; e < 4; ++e) denomLds[16 * pr + 4 * lq + e] = a2[e];
    }
    __syncthreads();
    #pragma unroll
    for (int k = 0; k < 2; ++k) {
        int pn = (w >> 1) + 2 * k;
        f32x4 acc = k ? a1 : a0;
        #pragma unroll
        for (int e = 0; e < 4; ++e) {
            int r_loc = 16 * pr + 4 * lq + e;
            og[(size_t)(i0 + r_loc) * DD + 16 * pn + ln] = acc[e] / denomLds[r_loc];
        }
    }
}

extern "C" void kernel_launch(void* const* d_in, const int* in_sizes, int n_in,
                              void* d_out, int out_size, void* d_ws, size_t ws_size,
                              hipStream_t stream) {
    const float* q   = (const float*)d_in[0];
    const float* k   = (const float*)d_in[1];
    const float* v   = (const float*)d_in[2];
    const float* rpe = (const float*)d_in[3];
    float* out = (float*)d_out;

    if (ws_size >= WS_NEED) {
        ushort_t* wsb = (ushort_t*)d_ws;
        float* wsPart = (float*)((char*)d_ws + OFF_P);
        hipLaunchKernelGGL(pre_kernel, dim3(CVT_BLOCKS + 256), dim3(256), 0, stream,
                           q, k, rpe, v, wsb);
        hipLaunchKernelGGL(fastmax_main, dim3(768), dim3(128), 0, stream, wsb, wsPart);
        hipLaunchKernelGGL(combine_kernel, dim3(512), dim3(256), 0, stream, wsPart, out);
    } else {
        hipLaunchKernelGGL(fastmax_fallback, dim3(512), dim3(256), 0, stream,
                           q, k, v, rpe, out);
    }
}